// Round 4
// baseline (293.080 us; speedup 1.0000x reference)
//
#include <hip/hip_runtime.h>

// LearnableGlobalLocalMultiheadAttention — round 16.
// r15 post-mortem: attn restored to 158 us (64 VGPR + accepted spills), total
// 288.9. attn is structure-bound (HBM 28%, VALU 46%, MFMA 2.8%, 6 barriers).
// r16 (attn only; cvt/proj/tail = r15 verbatim): fuse phases 4/4b/5/6 into ONE
// flash-style pass. S never materializes:
//   per jt-pair: S-tiles (same mask math) -> online row max/sum (rows kg*4+i
//   are thread-local in C-layout -> per-thread rescale) -> exp(s-m) fp16 ->
//   1.25 KB/wave LDS transpose stage (C-scatter write, A-layout b128 read) ->
//   PV MFMA accumulate. Epilogue folds 8 wave-partials with e^{m_w-M}, /Z.
// Removes: sc4 16-reg cross-barrier carry (the spill victim), phase 4b,
// phase 5 softmax, phase 6 Lh re-reads, 2 of 6 barriers. LDS 66->74.5 KB,
// still 2 blocks/CU.
//
// Algorithmic core (verified r1-11): triu*mini = kron(triu32,triu32)
// =>  A @ triu   == 2D inclusive prefix-sum of each row viewed as [32][32]
//     A @ triu^T == suffix sum; after softmax the 2D total == 1.0 exactly.

typedef _Float16 v8h __attribute__((ext_vector_type(8)));
typedef _Float16 v4h __attribute__((ext_vector_type(4)));
typedef _Float16 v2h __attribute__((ext_vector_type(2)));
typedef float    v4f __attribute__((ext_vector_type(4)));

#define SL 1048576   // halves per packed slice (32 bh * 1024 * 32)
#define RS 1032      // LDS row stride in fp16 elems (1024 + 8 pad)

static constexpr float SCALE = 0.17677669529663687f; // 32^-0.5

// ws layout (bytes):
//   [0, 18874368)         : 9 packed fp16 slices, slice i at i*SL halves
//       q-type {0,3,5,7} / k-type {1,4,6,8}: [bh][tile(64)][lane(64)][8]
//       slice 2 (v), PV-B: [bh][kc(32)][nt(2)][lane(64)][8]
//   [18874368, +4 MB)     : attn_pre fp32 [4096][256]
//   [23068672, +64 MB)    : pmask fp16 [32][64 rt][16384] fragment order:
//                           half index = jt*256 + lane*4 + i
//   [90177536, +6 MB)     : X16 fp16 {q,k,v} [4096][256] each
//   [96468992, +1.2 MB)   : W16 fp16 [2304][256]

// ---------------- Kernel 0: fp32 -> fp16 conversion (r12) ----------------
__global__ __launch_bounds__(256)
void cvt_kernel(const float* __restrict__ q, const float* __restrict__ k,
                const float* __restrict__ v, const float* __restrict__ W,
                _Float16* __restrict__ X16, _Float16* __restrict__ W16)
{
    const int b = blockIdx.x;
    const int t = threadIdx.x;
    const float* src; _Float16* dst; int off;
    if (b < 512)       { src = q; dst = X16;             off = b; }
    else if (b < 1024) { src = k; dst = X16 + (1 << 20); off = b - 512; }
    else if (b < 1536) { src = v; dst = X16 + (2 << 20); off = b - 1024; }
    else               { src = W; dst = W16;             off = b - 1536; }
    const int i = off * 2048 + t * 8;
    const float4 a = *(const float4*)(src + i);
    const float4 c = *(const float4*)(src + i + 4);
    v8h h;
    h[0] = (_Float16)a.x; h[1] = (_Float16)a.y; h[2] = (_Float16)a.z; h[3] = (_Float16)a.w;
    h[4] = (_Float16)c.x; h[5] = (_Float16)c.y; h[6] = (_Float16)c.z; h[7] = (_Float16)c.w;
    *(v8h*)(dst + i) = h;
}

// ---------------- Kernel 1: packed input projection (fp16 MFMA, r15) ----------------
__global__ __launch_bounds__(256)
void proj_kernel(const _Float16* __restrict__ X16, const _Float16* __restrict__ W16,
                 const float* __restrict__ bias, _Float16* __restrict__ P)
{
    __shared__ __align__(16) _Float16 stage[4096];   // 8 KB
    const int t  = threadIdx.x;
    const int n0 = blockIdx.x * 64;   // output column tile (0..2303)
    const int m0 = blockIdx.y * 64;   // row tile (0..4095), row = s*4 + b
    const int slice = n0 >> 8;        // uniform per block
    const int q2 = (n0 >> 6) & 3;     // 64-col quarter within slice
    const bool kslice = (slice == 1) || (slice == 4) || (slice == 6) || (slice == 8);
    const _Float16* X = X16 + (slice == 2 ? (2 << 20) : (kslice ? (1 << 20) : 0));
    const int w = t >> 6, lane = t & 63, m16 = lane & 15, kg = lane >> 4;
    const v4f zero = {0.f, 0.f, 0.f, 0.f};
    v4f acc[4] = {zero, zero, zero, zero};
    const _Float16* Arow = X + (size_t)(m0 + w * 16 + m16) * 256 + kg * 8;
    const _Float16* B0   = W16 + (size_t)(n0 + m16) * 256 + kg * 8;
#pragma unroll
    for (int kk = 0; kk < 8; ++kk) {
        const v8h a = *(const v8h*)(Arow + kk * 32);
#pragma unroll
        for (int nf = 0; nf < 4; ++nf) {
            const v8h bb = *(const v8h*)(B0 + nf * 4096 + kk * 32);
            acc[nf] = __builtin_amdgcn_mfma_f32_16x16x32_f16(a, bb, acc[nf], 0, 0, 0);
        }
    }
    const float scale = (slice == 0 || slice == 7) ? SCALE : 1.0f;
    // ---- stage into LDS with the packed-layout bijection ----
#pragma unroll
    for (int nf = 0; nf < 4; ++nf) {
        const int c = n0 + nf * 16 + m16;
        const float bv = bias[c];
#pragma unroll
        for (int i = 0; i < 4; ++i) {
            const _Float16 val = (_Float16)((acc[nf][i] + bv) * scale);
            const int lb = i * 2 + (nf >> 1);          // local bh 0..7
            int inner;
            if (slice == 2) {
                const int ls = w * 4 + kg;             // lm>>2 local row-quad
                inner = ((nf & 1) << 8) + ((ls >> 3) << 7) + m16 * 8 + (ls & 7);
            } else {
                inner = ((w * 4 + kg) + (((nf & 1) * 2 + (m16 >> 3)) << 4)) * 8 + (m16 & 7);
            }
            stage[lb * 512 + inner] = val;
        }
    }
    __syncthreads();
    // ---- coalesced copy-out: thread t -> 16 contiguous halves ----
    {
        const int o  = t * 16;
        const int lb = o >> 9;
        const int inner = o & 511;
        const int bs = lb >> 1, hh = lb & 1;
        const int bh = bs * 8 + 2 * q2 + hh;
        size_t dst;
        if (slice == 2) {
            const int kc = m0 >> 7;                    // s0>>5, constant per block
            const int g0 = (m0 >> 5) & 3;              // (s0>>3)&3, in {0,2}
            const int nt = inner >> 8, a = (inner >> 7) & 1, r = inner & 127;
            dst = (size_t)2 * SL + (size_t)bh * 32768
                + (size_t)(kc * 1024 + nt * 512 + (g0 + a) * 128 + r);
        } else {
            const int tile = m0 >> 6;
            dst = (size_t)slice * SL + (size_t)bh * 32768 + (size_t)(tile * 512 + inner);
        }
        *(v8h*)(P + dst)     = *(const v8h*)(stage + o);
        *(v8h*)(P + dst + 8) = *(const v8h*)(stage + o + 8);
    }
}

// ---------------- Kernel 2: fused MFMA attention (r16 flash-fused) ----------------
// 2048 blocks x 512 threads (8 waves): xcd = bid&7, q = bid>>3;
// bh = xcd*4 + (q&3), rt = q>>2. (512,4): 16 waves/CU target.
__global__ __launch_bounds__(512, 4)
void attn_kernel(const _Float16* __restrict__ P, float* __restrict__ attn_pre,
                 _Float16* __restrict__ pmask)
{
    __shared__ __align__(16) _Float16 Lh[16 * RS];
    __shared__ __align__(16) _Float16 Rh[16 * RS];
    __shared__ __align__(16) _Float16 STbuf[8 * 640];   // per-wave [16][40] stage, 10 KB

    const int t    = threadIdx.x;
    const int bid  = blockIdx.x;
    const int q    = bid >> 3;
    const int bh   = ((bid & 7) << 2) + (q & 3);
    const int rt   = q >> 2;
    const int w    = __builtin_amdgcn_readfirstlane(t >> 6);
    const int lane = t & 63;
    const int m16  = lane & 15;
    const int kg   = lane >> 4;

    const _Float16* Pb = P + (size_t)bh * 32768;
    const v4f zero = {0.f, 0.f, 0.f, 0.f};

    // ---- Phase 1: left/right logits via MFMA -> LDS fp16 ----
    {
        const v8h a_l = *(const v8h*)(Pb + 3 * SL + rt * 512 + lane * 8);
        const v8h a_r = *(const v8h*)(Pb + 5 * SL + rt * 512 + lane * 8);
        const _Float16* Bl = Pb + 4 * SL;
        const _Float16* Br = Pb + 6 * SL;
#pragma unroll 4
        for (int jt2 = 0; jt2 < 8; ++jt2) {
            const int jt = (w << 3) + jt2;
            const v8h bL = *(const v8h*)(Bl + jt * 512 + lane * 8);
            const v8h bR = *(const v8h*)(Br + jt * 512 + lane * 8);
            v4f cL = __builtin_amdgcn_mfma_f32_16x16x32_f16(a_l, bL, zero, 0, 0, 0);
            v4f cR = __builtin_amdgcn_mfma_f32_16x16x32_f16(a_r, bR, zero, 0, 0, 0);
            const int col = (jt << 4) + m16;
#pragma unroll
            for (int i = 0; i < 4; ++i) {
                Lh[((kg << 2) + i) * RS + col] = (_Float16)cL[i];
                Rh[((kg << 2) + i) * RS + col] = (_Float16)cR[i];
            }
        }
    }
    __syncthreads();

    // ---- Phase 2: softmax per row, no max pass (logits O(+-15), fp32 exp) ----
    auto softmax_pairs = [&](_Float16* ROW) {
        float v0[8], v1[8];
        float ss = 0.f;
#pragma unroll
        for (int kq = 0; kq < 8; ++kq) {
            const v2h pr = *(const v2h*)&ROW[(lane + (kq << 6)) << 1];
            v0[kq] = __expf((float)pr[0]);
            v1[kq] = __expf((float)pr[1]);
            ss += v0[kq] + v1[kq];
        }
#pragma unroll
        for (int off = 32; off; off >>= 1) ss += __shfl_xor(ss, off);
        const float inv = 1.f / ss;
#pragma unroll
        for (int kq = 0; kq < 8; ++kq) {
            v2h pr; pr[0] = (_Float16)(v0[kq] * inv); pr[1] = (_Float16)(v1[kq] * inv);
            *(v2h*)&ROW[(lane + (kq << 6)) << 1] = pr;
        }
    };
#pragma unroll
    for (int r = 0; r < 2; ++r) {
        softmax_pairs(&Lh[((w << 1) + r) * RS]);
        softmax_pairs(&Rh[((w << 1) + r) * RS]);
    }
    // no barrier: phase 3 touches the same rows from the same wave.

    // ---- Phase 3: fused 2D inclusive prefix scan (lanes<32: L, >=32: R) ----
    {
        const int kr = lane & 31;
#pragma unroll
        for (int r = 0; r < 2; ++r) {
            _Float16* ROW = (lane >= 32) ? &Rh[((w << 1) + r) * RS] : &Lh[((w << 1) + r) * RS];
            float run = 0.f;
#pragma unroll 4
            for (int kb = 0; kb < 32; ++kb) {
                float x = (float)ROW[(kb << 5) + kr];
#pragma unroll
                for (int off = 1; off < 32; off <<= 1) {
                    float y = __shfl_up(x, off, 32);
                    if (kr >= off) x += y;
                }
                run += x;                       // P(kb,kr)
                ROW[(kb << 5) + kr] = (_Float16)run;
            }
        }
    }
    __syncthreads();

    // ---- Phase 4 (fused): logits + mask + online softmax + PV, per-wave k=128 ----
    {
        _Float16* pm = pmask + (size_t)bh * 1048576 + (size_t)rt * 16384;
        const v8h a_g = *(const v8h*)(Pb + 0 * SL + rt * 512 + lane * 8);
        const v8h a_c = *(const v8h*)(Pb + 7 * SL + rt * 512 + lane * 8);
        const _Float16* Bg = Pb + 1 * SL;
        const _Float16* Bc = Pb + 8 * SL;
        const _Float16* Vb = Pb + 2 * SL;
        _Float16* STw = &STbuf[w * 640];        // [16 rows][40 halves]
        v4f acc0 = zero, acc1 = zero;
        float mrow[4] = {-1e30f, -1e30f, -1e30f, -1e30f};
        float zrow[4] = {0.f, 0.f, 0.f, 0.f};
#pragma unroll
        for (int p = 0; p < 4; ++p) {
            const int kc = (w << 2) + p;        // jt>>1 for both tiles of the pair
            v4f s8[2];
#pragma unroll
            for (int e = 0; e < 2; ++e) {
                const int jt  = (w << 3) + (p << 1) + e;
                const int jb  = kc;
                const int jr  = ((jt & 1) << 4) + m16;
                const int col = (jt << 4) + m16;
                const v8h bG = *(const v8h*)(Bg + jt * 512 + lane * 8);
                const v8h bC = *(const v8h*)(Bc + jt * 512 + lane * 8);
                const v4f g4 = __builtin_amdgcn_mfma_f32_16x16x32_f16(a_g, bG, zero, 0, 0, 0);
                const v4f l4 = __builtin_amdgcn_mfma_f32_16x16x32_f16(a_c, bC, zero, 0, 0, 0);
                v4h m4;
                v4f s4;
#pragma unroll
                for (int i = 0; i < 4; ++i) {
                    const int rr = ((kg << 2) + i) * RS;
                    const float PL  = (float)Lh[rr + col];
                    const float PR  = (float)Rh[rr + col];
                    const float eLb = jb ? (float)Lh[rr + (jb << 5) - 1] : 0.f;
                    const float eRb = jb ? (float)Rh[rr + (jb << 5) - 1] : 0.f;
                    const float eLc = jr ? (float)Lh[rr + 991 + jr] : 0.f;
                    const float eRc = jr ? (float)Rh[rr + 991 + jr] : 0.f;
                    const float eLbc = (jb && jr) ? (float)Lh[rr + ((jb - 1) << 5) + jr - 1] : 0.f;
                    const float eRbc = (jb && jr) ? (float)Rh[rr + ((jb - 1) << 5) + jr - 1] : 0.f;
                    const float SLv = 1.0f - eLb - eLc + eLbc;
                    const float SRv = 1.0f - eRb - eRc + eRbc;
                    const float mkv = PL * SRv + SLv * PR;
                    s4[i] = 0.1f * g4[i] + l4[i] * mkv;
                    m4[i] = (_Float16)mkv;
                }
                s8[e] = s4;
                *(v4h*)(pm + ((size_t)jt << 8) + (lane << 2)) = m4;   // coalesced 8 B/lane
            }
            // online row stats (rows kg*4+i are thread-local in C-layout)
            float f[4];
#pragma unroll
            for (int i = 0; i < 4; ++i) {
                float tm = fmaxf(s8[0][i], s8[1][i]);
                tm = fmaxf(tm, __shfl_xor(tm, 1));
                tm = fmaxf(tm, __shfl_xor(tm, 2));
                tm = fmaxf(tm, __shfl_xor(tm, 4));
                tm = fmaxf(tm, __shfl_xor(tm, 8));
                const float mn = fmaxf(mrow[i], tm);
                f[i] = __expf(mrow[i] - mn);
                mrow[i] = mn;
            }
#pragma unroll
            for (int i = 0; i < 4; ++i) {
                const float p0 = __expf(s8[0][i] - mrow[i]);
                const float p1 = __expf(s8[1][i] - mrow[i]);
                STw[((kg << 2) + i) * 40 + m16]      = (_Float16)p0;   // C-scatter
                STw[((kg << 2) + i) * 40 + 16 + m16] = (_Float16)p1;
                float zs = p0 + p1;
                zs += __shfl_xor(zs, 1);
                zs += __shfl_xor(zs, 2);
                zs += __shfl_xor(zs, 4);
                zs += __shfl_xor(zs, 8);
                zrow[i] = zrow[i] * f[i] + zs;
                acc0[i] *= f[i];
                acc1[i] *= f[i];
            }
            // A-layout read (row m16, k-window 32) + PV MFMA
            const v8h pa  = *(const v8h*)(STw + m16 * 40 + kg * 8);
            const v8h bv0 = *(const v8h*)(Vb + (size_t)(kc * 2 + 0) * 512 + lane * 8);
            const v8h bv1 = *(const v8h*)(Vb + (size_t)(kc * 2 + 1) * 512 + lane * 8);
            acc0 = __builtin_amdgcn_mfma_f32_16x16x32_f16(pa, bv0, acc0, 0, 0, 0);
            acc1 = __builtin_amdgcn_mfma_f32_16x16x32_f16(pa, bv1, acc1, 0, 0, 0);
        }
        // publish per-wave z/m into own (now dead) stage region, pre-barrier
        float* zm = (float*)STw;
        if (m16 == 0) {
#pragma unroll
            for (int i = 0; i < 4; ++i) {
                zm[((kg << 2) + i) * 2]     = zrow[i];
                zm[((kg << 2) + i) * 2 + 1] = mrow[i];
            }
        }
        __syncthreads();   // all scan reads done; Rh becomes dead
        float* Pbuf = (float*)&Rh[0];
#pragma unroll
        for (int i = 0; i < 4; ++i) {
            Pbuf[(((w << 1) + 0) << 8) + (lane << 2) + i] = acc0[i];
            Pbuf[(((w << 1) + 1) << 8) + (lane << 2) + i] = acc1[i];
        }
    }
    __syncthreads();

    // ---- Epilogue: fold 8 wave-partials with e^{m_w-M}, divide by Z ----
    {
        const float* Pbuf = (const float*)&Rh[0];
        const int r   = t >> 5;                    // row in tile (0..15)
        const int d   = t & 31;
        const int nt2 = d >> 4, n = d & 15;
        const int off = ((r >> 2) << 6) + (n << 2) + (r & 3);
        float M = -1e30f;
#pragma unroll
        for (int w8 = 0; w8 < 8; ++w8)
            M = fmaxf(M, ((const float*)&STbuf[w8 * 640])[r * 2 + 1]);
        float Z = 0.f, v = 0.f;
#pragma unroll
        for (int w8 = 0; w8 < 8; ++w8) {
            const float* zm8 = (const float*)&STbuf[w8 * 640];
            const float sc = __expf(zm8[r * 2 + 1] - M);
            Z += zm8[r * 2] * sc;
            v += Pbuf[(((w8 << 1) + nt2) << 8) + off] * sc;
        }
        const int srow = (rt << 4) + r;
        attn_pre[((size_t)(srow * 4 + (bh >> 3))) * 256 + (bh & 7) * 32 + d] = v / Z;
    }
}

// ---------------- Kernel 3: fused tail — outproj (blocks 0..255) + cmask (256..767) ----
__global__ __launch_bounds__(256)
void tail_kernel(const _Float16* __restrict__ pmask, float* __restrict__ cmask,
                 const float* __restrict__ A, const float* __restrict__ W,
                 const float* __restrict__ bias, float* __restrict__ C)
{
    __shared__ __align__(16) float SMEM[4 * 16 * 132];   // 33792 B
    const int bid = blockIdx.x;
    const int t = threadIdx.x;

    if (bid >= 256) {
        // ---- cmask part: 512 blocks, grid-equivalent (64 rt, 8 wh) ----
        const int b2 = bid - 256;
        const int rt = b2 >> 3, wh = b2 & 7;
        float (*T4)[16][132] = (float(*)[16][132])SMEM;
        const int wv = t >> 6;                            // wave -> bh octet
        const int lane = t & 63, m16 = lane & 15, kg = lane >> 4;
        float acc[8][4] = {};
        const _Float16* base = pmask + (size_t)rt * 16384 + ((size_t)wh << 11) + (lane << 2)
                             + ((size_t)wv << 3) * 1048576;
        for (int bh = 0; bh < 8; ++bh) {
            const _Float16* p = base + (size_t)bh * 1048576;
#pragma unroll
            for (int jt2 = 0; jt2 < 8; ++jt2) {
                const v4h h4 = *(const v4h*)(p + (jt2 << 8));
#pragma unroll
                for (int i = 0; i < 4; ++i) acc[jt2][i] += (float)h4[i];
            }
        }
#pragma unroll
        for (int jt2 = 0; jt2 < 8; ++jt2)
#pragma unroll
            for (int i = 0; i < 4; ++i)
                T4[wv][(kg << 2) + i][(jt2 << 4) + m16] = acc[jt2][i];
        __syncthreads();
        // 16 rows x 128 cols; thread t -> row t>>4, 8 consecutive cols.
        const int row = t >> 4;
        const int c0  = (t & 15) << 3;
#pragma unroll
        for (int h = 0; h < 2; ++h) {
            const int c = c0 + (h << 2);
            const float4 s0 = *(const float4*)&T4[0][row][c];
            const float4 s1 = *(const float4*)&T4[1][row][c];
            const float4 s2 = *(const float4*)&T4[2][row][c];
            const float4 s3 = *(const float4*)&T4[3][row][c];
            const float4 o = make_float4(s0.x + s1.x + s2.x + s3.x,
                                         s0.y + s1.y + s2.y + s3.y,
                                         s0.z + s1.z + s2.z + s3.z,
                                         s0.w + s1.w + s2.w + s3.w);
            *(float4*)&cmask[((size_t)((rt << 4) + row) << 10) + (wh << 7) + c] = o;
        }
    } else {
        // ---- outproj part: 256 blocks, grid-equivalent (4 n0, 64 m0) ----
        const int n0 = (bid & 3) * 64;
        const int m0 = (bid >> 2) * 64;
        float (*As)[68] = (float(*)[68])SMEM;
        float (*Bs)[68] = (float(*)[68])(SMEM + 16 * 68);
        const int tx = t & 15, ty = t >> 4;
        const int lm = t >> 2, lk = (t & 3) << 2;
        float acc[4][4] = {};
        for (int k0 = 0; k0 < 256; k0 += 16) {
            float4 av = *(const float4*)(A + (size_t)(m0 + lm) * 256 + k0 + lk);
            float4 bv = *(const float4*)(W + (size_t)(n0 + lm) * 256 + k0 + lk);
            As[lk + 0][lm] = av.x; As[lk + 1][lm] = av.y; As[lk + 2][lm] = av.z; As[lk + 3][lm] = av.w;
            Bs[lk + 0][lm] = bv.x; Bs[lk + 1][lm] = bv.y; Bs[lk + 2][lm] = bv.z; Bs[lk + 3][lm] = bv.w;
            __syncthreads();
#pragma unroll
            for (int kk = 0; kk < 16; ++kk) {
                float4 a4 = *(const float4*)&As[kk][ty << 2];
                float4 b4 = *(const float4*)&Bs[kk][tx << 2];
                float aa[4] = {a4.x, a4.y, a4.z, a4.w};
                float bb[4] = {b4.x, b4.y, b4.z, b4.w};
#pragma unroll
                for (int i = 0; i < 4; ++i)
#pragma unroll
                    for (int j = 0; j < 4; ++j)
                        acc[i][j] = fmaf(aa[i], bb[j], acc[i][j]);
            }
            __syncthreads();
        }
#pragma unroll
        for (int i = 0; i < 4; ++i) {
            const int m  = m0 + (ty << 2) + i;
            const int c0 = n0 + (tx << 2);
            float4 o = make_float4(acc[i][0] + bias[c0 + 0], acc[i][1] + bias[c0 + 1],
                                   acc[i][2] + bias[c0 + 2], acc[i][3] + bias[c0 + 3]);
            *(float4*)&C[(size_t)m * 256 + c0] = o;
        }
    }
}

extern "C" void kernel_launch(void* const* d_in, const int* in_sizes, int n_in,
                              void* d_out, int out_size, void* d_ws, size_t ws_size,
                              hipStream_t stream)
{
    const float* q  = (const float*)d_in[0];
    const float* k  = (const float*)d_in[1];
    const float* v  = (const float*)d_in[2];
    const float* Wi = (const float*)d_in[3];
    const float* bi = (const float*)d_in[4];
    const float* Wo = (const float*)d_in[5];
    const float* bo = (const float*)d_in[6];

    float* out      = (float*)d_out;
    float* attn_out = out;                 // [1024,4,256]
    float* cmask    = out + 1048576;       // [1024,1024]

    _Float16* Ppack    = (_Float16*)d_ws;
    float*    attn_pre = (float*)((char*)d_ws + 18874368);
    _Float16* pmask    = (_Float16*)((char*)d_ws + 23068672);
    _Float16* X16      = (_Float16*)((char*)d_ws + 90177536);
    _Float16* W16      = (_Float16*)((char*)d_ws + 96468992);

    cvt_kernel<<<1824, 256, 0, stream>>>(q, k, v, Wi, X16, W16);
    proj_kernel<<<dim3(36, 64), 256, 0, stream>>>(X16, W16, bi, Ppack);
    attn_kernel<<<2048, 512, 0, stream>>>(Ppack, attn_pre, pmask);
    tail_kernel<<<768, 256, 0, stream>>>(pmask, cmask, attn_pre, Wo, bo, attn_out);
}

// Round 5
// 276.738 us; speedup vs baseline: 1.0591x; 1.0591x over previous
//
#include <hip/hip_runtime.h>

// LearnableGlobalLocalMultiheadAttention — round 17.
// r16 post-mortem: flash fusion cut traffic 359->190 MB but dur ROSE 158->167
// => attn latency-bound on serial structure, insensitive to HBM traffic
// (359MB@158, 190MB@167, 80MB@210). Revert to r15-best attn; change ONLY
// phases 2+3: fuse softmax+2D-scan into ONE register pass per row.
//   old: ph2 (read+exp+reduce+write) then ph3: 32 SEQUENTIAL kb iters, each
//        LDS-read -> 5-deep shfl chain -> LDS-write feeding next iter (~4-5K
//        cy serial per row, between barriers).
//   new: lane kr loads x[32] (independent reads), exp f32, kr-scan 5 shfls
//        x32 kb INDEPENDENT (ILP), cross-kb prefix = 31 in-lane adds (~124
//        cy, only serial part), total = shfl(x[31],31) == softmax denom
//        (2D total identity), scale once, write fp16 once. LDS ops/elem 4->2.
// Predict: attn 158 -> ~135-145 us, traffic unchanged, bank-conflict < 917K.
//
// Algorithmic core (verified r1-11): triu*mini = kron(triu32,triu32)
// =>  A @ triu   == 2D inclusive prefix-sum of each row viewed as [32][32]
//     A @ triu^T == suffix sum; after softmax the 2D total == 1.0 exactly.

typedef _Float16 v8h __attribute__((ext_vector_type(8)));
typedef _Float16 v4h __attribute__((ext_vector_type(4)));
typedef _Float16 v2h __attribute__((ext_vector_type(2)));
typedef float    v4f __attribute__((ext_vector_type(4)));

#define SL 1048576   // halves per packed slice (32 bh * 1024 * 32)
#define RS 1032      // LDS row stride in fp16 elems (1024 + 8 pad)

static constexpr float SCALE = 0.17677669529663687f; // 32^-0.5

// ws layout (bytes):
//   [0, 18874368)         : 9 packed fp16 slices, slice i at i*SL halves
//       q-type {0,3,5,7} / k-type {1,4,6,8}: [bh][tile(64)][lane(64)][8]
//       slice 2 (v), PV-B: [bh][kc(32)][nt(2)][lane(64)][8]
//   [18874368, +4 MB)     : attn_pre fp32 [4096][256]
//   [23068672, +64 MB)    : pmask fp16 [32][64 rt][16384] fragment order:
//                           half index = jt*256 + lane*4 + i
//   [90177536, +6 MB)     : X16 fp16 {q,k,v} [4096][256] each
//   [96468992, +1.2 MB)   : W16 fp16 [2304][256]

// ---------------- Kernel 0: fp32 -> fp16 conversion (r12) ----------------
__global__ __launch_bounds__(256)
void cvt_kernel(const float* __restrict__ q, const float* __restrict__ k,
                const float* __restrict__ v, const float* __restrict__ W,
                _Float16* __restrict__ X16, _Float16* __restrict__ W16)
{
    const int b = blockIdx.x;
    const int t = threadIdx.x;
    const float* src; _Float16* dst; int off;
    if (b < 512)       { src = q; dst = X16;             off = b; }
    else if (b < 1024) { src = k; dst = X16 + (1 << 20); off = b - 512; }
    else if (b < 1536) { src = v; dst = X16 + (2 << 20); off = b - 1024; }
    else               { src = W; dst = W16;             off = b - 1536; }
    const int i = off * 2048 + t * 8;
    const float4 a = *(const float4*)(src + i);
    const float4 c = *(const float4*)(src + i + 4);
    v8h h;
    h[0] = (_Float16)a.x; h[1] = (_Float16)a.y; h[2] = (_Float16)a.z; h[3] = (_Float16)a.w;
    h[4] = (_Float16)c.x; h[5] = (_Float16)c.y; h[6] = (_Float16)c.z; h[7] = (_Float16)c.w;
    *(v8h*)(dst + i) = h;
}

// ---------------- Kernel 1: packed input projection (fp16 MFMA, r15) ----------------
__global__ __launch_bounds__(256)
void proj_kernel(const _Float16* __restrict__ X16, const _Float16* __restrict__ W16,
                 const float* __restrict__ bias, _Float16* __restrict__ P)
{
    __shared__ __align__(16) _Float16 stage[4096];   // 8 KB
    const int t  = threadIdx.x;
    const int n0 = blockIdx.x * 64;   // output column tile (0..2303)
    const int m0 = blockIdx.y * 64;   // row tile (0..4095), row = s*4 + b
    const int slice = n0 >> 8;        // uniform per block
    const int q2 = (n0 >> 6) & 3;     // 64-col quarter within slice
    const bool kslice = (slice == 1) || (slice == 4) || (slice == 6) || (slice == 8);
    const _Float16* X = X16 + (slice == 2 ? (2 << 20) : (kslice ? (1 << 20) : 0));
    const int w = t >> 6, lane = t & 63, m16 = lane & 15, kg = lane >> 4;
    const v4f zero = {0.f, 0.f, 0.f, 0.f};
    v4f acc[4] = {zero, zero, zero, zero};
    const _Float16* Arow = X + (size_t)(m0 + w * 16 + m16) * 256 + kg * 8;
    const _Float16* B0   = W16 + (size_t)(n0 + m16) * 256 + kg * 8;
#pragma unroll
    for (int kk = 0; kk < 8; ++kk) {
        const v8h a = *(const v8h*)(Arow + kk * 32);
#pragma unroll
        for (int nf = 0; nf < 4; ++nf) {
            const v8h bb = *(const v8h*)(B0 + nf * 4096 + kk * 32);
            acc[nf] = __builtin_amdgcn_mfma_f32_16x16x32_f16(a, bb, acc[nf], 0, 0, 0);
        }
    }
    const float scale = (slice == 0 || slice == 7) ? SCALE : 1.0f;
    // ---- stage into LDS with the packed-layout bijection ----
#pragma unroll
    for (int nf = 0; nf < 4; ++nf) {
        const int c = n0 + nf * 16 + m16;
        const float bv = bias[c];
#pragma unroll
        for (int i = 0; i < 4; ++i) {
            const _Float16 val = (_Float16)((acc[nf][i] + bv) * scale);
            const int lb = i * 2 + (nf >> 1);          // local bh 0..7
            int inner;
            if (slice == 2) {
                const int ls = w * 4 + kg;             // lm>>2 local row-quad
                inner = ((nf & 1) << 8) + ((ls >> 3) << 7) + m16 * 8 + (ls & 7);
            } else {
                inner = ((w * 4 + kg) + (((nf & 1) * 2 + (m16 >> 3)) << 4)) * 8 + (m16 & 7);
            }
            stage[lb * 512 + inner] = val;
        }
    }
    __syncthreads();
    // ---- coalesced copy-out: thread t -> 16 contiguous halves ----
    {
        const int o  = t * 16;
        const int lb = o >> 9;
        const int inner = o & 511;
        const int bs = lb >> 1, hh = lb & 1;
        const int bh = bs * 8 + 2 * q2 + hh;
        size_t dst;
        if (slice == 2) {
            const int kc = m0 >> 7;                    // s0>>5, constant per block
            const int g0 = (m0 >> 5) & 3;              // (s0>>3)&3, in {0,2}
            const int nt = inner >> 8, a = (inner >> 7) & 1, r = inner & 127;
            dst = (size_t)2 * SL + (size_t)bh * 32768
                + (size_t)(kc * 1024 + nt * 512 + (g0 + a) * 128 + r);
        } else {
            const int tile = m0 >> 6;
            dst = (size_t)slice * SL + (size_t)bh * 32768 + (size_t)(tile * 512 + inner);
        }
        *(v8h*)(P + dst)     = *(const v8h*)(stage + o);
        *(v8h*)(P + dst + 8) = *(const v8h*)(stage + o + 8);
    }
}

// ---------------- Kernel 2: fused MFMA attention (r15 + register scan) ----------------
// 2048 blocks x 512 threads (8 waves): xcd = bid&7, q = bid>>3;
// bh = xcd*4 + (q&3), rt = q>>2. (512,4): 16 waves/CU. Phase 4 single-pass,
// FULL unroll (spills accepted — measured-best). Phases 2+3 fused in regs.
__global__ __launch_bounds__(512, 4)
void attn_kernel(const _Float16* __restrict__ P, float* __restrict__ attn_pre,
                 _Float16* __restrict__ pmask)
{
    __shared__ __align__(16) _Float16 Lh[16 * RS];
    __shared__ __align__(16) _Float16 Rh[16 * RS];

    const int t    = threadIdx.x;
    const int bid  = blockIdx.x;
    const int q    = bid >> 3;
    const int bh   = ((bid & 7) << 2) + (q & 3);
    const int rt   = q >> 2;
    const int w    = __builtin_amdgcn_readfirstlane(t >> 6);
    const int lane = t & 63;
    const int m16  = lane & 15;
    const int kg   = lane >> 4;

    const _Float16* Pb = P + (size_t)bh * 32768;
    const v4f zero = {0.f, 0.f, 0.f, 0.f};

    // ---- Phase 1: left/right logits via MFMA -> LDS fp16 ----
    {
        const v8h a_l = *(const v8h*)(Pb + 3 * SL + rt * 512 + lane * 8);
        const v8h a_r = *(const v8h*)(Pb + 5 * SL + rt * 512 + lane * 8);
        const _Float16* Bl = Pb + 4 * SL;
        const _Float16* Br = Pb + 6 * SL;
#pragma unroll 4
        for (int jt2 = 0; jt2 < 8; ++jt2) {
            const int jt = (w << 3) + jt2;
            const v8h bL = *(const v8h*)(Bl + jt * 512 + lane * 8);
            const v8h bR = *(const v8h*)(Br + jt * 512 + lane * 8);
            v4f cL = __builtin_amdgcn_mfma_f32_16x16x32_f16(a_l, bL, zero, 0, 0, 0);
            v4f cR = __builtin_amdgcn_mfma_f32_16x16x32_f16(a_r, bR, zero, 0, 0, 0);
            const int col = (jt << 4) + m16;
#pragma unroll
            for (int i = 0; i < 4; ++i) {
                Lh[((kg << 2) + i) * RS + col] = (_Float16)cL[i];
                Rh[((kg << 2) + i) * RS + col] = (_Float16)cR[i];
            }
        }
    }
    __syncthreads();

    // ---- Phase 2+3 fused: softmax + 2D inclusive scan, register-resident ----
    // lanes<32: L rows, lanes>=32: R rows; lane kr owns cols {kb*32+kr}.
    // exp -> kr-scan (5 shfls x32 kb, ILP) -> in-lane kb-prefix (31 adds,
    // only serial part) -> total=shfl(x[31],31) (2D total == softmax denom)
    // -> single scaled fp16 write. One LDS read + one write per element.
    {
        const int kr = lane & 31;
        for (int r = 0; r < 2; ++r) {
            _Float16* ROW = (lane >= 32) ? &Rh[((w << 1) + r) * RS] : &Lh[((w << 1) + r) * RS];
            float x[32];
#pragma unroll
            for (int kb = 0; kb < 32; ++kb)
                x[kb] = __expf((float)ROW[(kb << 5) + kr]);
#pragma unroll
            for (int kb = 0; kb < 32; ++kb) {
#pragma unroll
                for (int off = 1; off < 32; off <<= 1) {
                    const float y = __shfl_up(x[kb], off, 32);
                    if (kr >= off) x[kb] += y;
                }
            }
#pragma unroll
            for (int kb = 1; kb < 32; ++kb) x[kb] += x[kb - 1];
            const float inv = 1.f / __shfl(x[31], 31, 32);
#pragma unroll
            for (int kb = 0; kb < 32; ++kb)
                ROW[(kb << 5) + kr] = (_Float16)(x[kb] * inv);
        }
    }
    __syncthreads();

    // ---- Phase 4: single pass, FULL unroll — g/c MFMAs + mask combine;
    // mk -> pmask direct; sc4 sole cross-barrier state; 2D total == 1.0. ----
    v4h sc4[8];
    {
        _Float16* pm = pmask + (size_t)bh * 1048576 + (size_t)rt * 16384;
        const v8h a_g = *(const v8h*)(Pb + 0 * SL + rt * 512 + lane * 8);
        const v8h a_c = *(const v8h*)(Pb + 7 * SL + rt * 512 + lane * 8);
        const _Float16* Bg = Pb + 1 * SL;
        const _Float16* Bc = Pb + 8 * SL;
#pragma unroll
        for (int jt2 = 0; jt2 < 8; ++jt2) {
            const int jt  = (w << 3) + jt2;
            const int jb  = jt >> 1;
            const int jr  = ((jt & 1) << 4) + m16;
            const int col = (jt << 4) + m16;
            const v8h bG = *(const v8h*)(Bg + jt * 512 + lane * 8);
            const v8h bC = *(const v8h*)(Bc + jt * 512 + lane * 8);
            const v4f g4 = __builtin_amdgcn_mfma_f32_16x16x32_f16(a_g, bG, zero, 0, 0, 0);
            const v4f l4 = __builtin_amdgcn_mfma_f32_16x16x32_f16(a_c, bC, zero, 0, 0, 0);
            v4h s4, m4;
#pragma unroll
            for (int i = 0; i < 4; ++i) {
                const int rr = ((kg << 2) + i) * RS;
                const float PL  = (float)Lh[rr + col];
                const float PR  = (float)Rh[rr + col];
                const float eLb = jb ? (float)Lh[rr + (jb << 5) - 1] : 0.f;
                const float eRb = jb ? (float)Rh[rr + (jb << 5) - 1] : 0.f;
                const float eLc = jr ? (float)Lh[rr + 991 + jr] : 0.f;
                const float eRc = jr ? (float)Rh[rr + 991 + jr] : 0.f;
                const float eLbc = (jb && jr) ? (float)Lh[rr + ((jb - 1) << 5) + jr - 1] : 0.f;
                const float eRbc = (jb && jr) ? (float)Rh[rr + ((jb - 1) << 5) + jr - 1] : 0.f;
                const float SLv = 1.0f - eLb - eLc + eLbc;
                const float SRv = 1.0f - eRb - eRc + eRbc;
                const float mkv = PL * SRv + SLv * PR;
                s4[i] = (_Float16)(0.1f * g4[i] + l4[i] * mkv);
                m4[i] = (_Float16)mkv;
            }
            sc4[jt2] = s4;
            *(v4h*)(pm + ((size_t)jt << 8) + (lane << 2)) = m4;   // coalesced 8 B/lane
        }
    }
    __syncthreads();   // all scan reads complete before overwrite

    // ---- Phase 4b: write S -> Lh ----
    {
#pragma unroll
        for (int jt2 = 0; jt2 < 8; ++jt2) {
            const int col = ((((w << 3) + jt2)) << 4) + m16;
#pragma unroll
            for (int i = 0; i < 4; ++i)
                Lh[((kg << 2) + i) * RS + col] = sc4[jt2][i];
        }
    }
    __syncthreads();

    // ---- Phase 5: final softmax on S ----
    auto softmax_pairs = [&](_Float16* ROW) {
        float v0[8], v1[8];
        float ss = 0.f;
#pragma unroll
        for (int kq = 0; kq < 8; ++kq) {
            const v2h pr = *(const v2h*)&ROW[(lane + (kq << 6)) << 1];
            v0[kq] = __expf((float)pr[0]);
            v1[kq] = __expf((float)pr[1]);
            ss += v0[kq] + v1[kq];
        }
#pragma unroll
        for (int off = 32; off; off >>= 1) ss += __shfl_xor(ss, off);
        const float inv = 1.f / ss;
#pragma unroll
        for (int kq = 0; kq < 8; ++kq) {
            v2h pr; pr[0] = (_Float16)(v0[kq] * inv); pr[1] = (_Float16)(v1[kq] * inv);
            *(v2h*)&ROW[(lane + (kq << 6)) << 1] = pr;
        }
    };
#pragma unroll
    for (int r = 0; r < 2; ++r) softmax_pairs(&Lh[((w << 1) + r) * RS]);
    __syncthreads();

    // ---- Phase 6: PV via MFMA. wave = (nt = d-half, hf = j-quarter) ----
    {
        const int nt = w & 1, hf = w >> 1;
        v4f c = zero;
        const _Float16* Vb = Pb + 2 * SL + nt * 512 + lane * 8;
        const int kc0 = hf << 3;
#pragma unroll 4
        for (int kc2 = 0; kc2 < 8; ++kc2) {
            const int kc = kc0 + kc2;
            const v8h a = *(const v8h*)&Lh[m16 * RS + (kc << 5) + (kg << 3)];
            const v8h b = *(const v8h*)(Vb + (size_t)kc * 1024);
            c = __builtin_amdgcn_mfma_f32_16x16x32_f16(a, b, c, 0, 0, 0);
        }
        float* Pbuf = (float*)&Rh[0];   // Rh dead since phase-4 barrier
#pragma unroll
        for (int i = 0; i < 4; ++i) Pbuf[(w << 8) + (lane << 2) + i] = c[i];
    }
    __syncthreads();

    // ---- Epilogue: fold 4 j-quarters, coalesced d-fastest store ----
    {
        const float* Pbuf = (const float*)&Rh[0];
        const int r   = t >> 5;                    // row in tile (0..15)
        const int d   = t & 31;
        const int nt2 = d >> 4, n = d & 15;
        const int kg2 = r >> 2, i2 = r & 3;
        const int off = (kg2 << 6) + (n << 2) + i2;   // lane*4 + i
        float v = 0.f;
#pragma unroll
        for (int hf = 0; hf < 4; ++hf)
            v += Pbuf[(((hf << 1) + nt2) << 8) + off];
        const int srow = (rt << 4) + r;
        attn_pre[((size_t)(srow * 4 + (bh >> 3))) * 256 + (bh & 7) * 32 + d] = v;
    }
}

// ---------------- Kernel 3: fused tail — outproj (blocks 0..255) + cmask (256..767) ----
__global__ __launch_bounds__(256)
void tail_kernel(const _Float16* __restrict__ pmask, float* __restrict__ cmask,
                 const float* __restrict__ A, const float* __restrict__ W,
                 const float* __restrict__ bias, float* __restrict__ C)
{
    __shared__ __align__(16) float SMEM[4 * 16 * 132];   // 33792 B
    const int bid = blockIdx.x;
    const int t = threadIdx.x;

    if (bid >= 256) {
        // ---- cmask part: 512 blocks, grid-equivalent (64 rt, 8 wh) ----
        const int b2 = bid - 256;
        const int rt = b2 >> 3, wh = b2 & 7;
        float (*T4)[16][132] = (float(*)[16][132])SMEM;
        const int wv = t >> 6;                            // wave -> bh octet
        const int lane = t & 63, m16 = lane & 15, kg = lane >> 4;
        float acc[8][4] = {};
        const _Float16* base = pmask + (size_t)rt * 16384 + ((size_t)wh << 11) + (lane << 2)
                             + ((size_t)wv << 3) * 1048576;
        for (int bh = 0; bh < 8; ++bh) {
            const _Float16* p = base + (size_t)bh * 1048576;
#pragma unroll
            for (int jt2 = 0; jt2 < 8; ++jt2) {
                const v4h h4 = *(const v4h*)(p + (jt2 << 8));
#pragma unroll
                for (int i = 0; i < 4; ++i) acc[jt2][i] += (float)h4[i];
            }
        }
#pragma unroll
        for (int jt2 = 0; jt2 < 8; ++jt2)
#pragma unroll
            for (int i = 0; i < 4; ++i)
                T4[wv][(kg << 2) + i][(jt2 << 4) + m16] = acc[jt2][i];
        __syncthreads();
        // 16 rows x 128 cols; thread t -> row t>>4, 8 consecutive cols.
        const int row = t >> 4;
        const int c0  = (t & 15) << 3;
#pragma unroll
        for (int h = 0; h < 2; ++h) {
            const int c = c0 + (h << 2);
            const float4 s0 = *(const float4*)&T4[0][row][c];
            const float4 s1 = *(const float4*)&T4[1][row][c];
            const float4 s2 = *(const float4*)&T4[2][row][c];
            const float4 s3 = *(const float4*)&T4[3][row][c];
            const float4 o = make_float4(s0.x + s1.x + s2.x + s3.x,
                                         s0.y + s1.y + s2.y + s3.y,
                                         s0.z + s1.z + s2.z + s3.z,
                                         s0.w + s1.w + s2.w + s3.w);
            *(float4*)&cmask[((size_t)((rt << 4) + row) << 10) + (wh << 7) + c] = o;
        }
    } else {
        // ---- outproj part: 256 blocks, grid-equivalent (4 n0, 64 m0) ----
        const int n0 = (bid & 3) * 64;
        const int m0 = (bid >> 2) * 64;
        float (*As)[68] = (float(*)[68])SMEM;
        float (*Bs)[68] = (float(*)[68])(SMEM + 16 * 68);
        const int tx = t & 15, ty = t >> 4;
        const int lm = t >> 2, lk = (t & 3) << 2;
        float acc[4][4] = {};
        for (int k0 = 0; k0 < 256; k0 += 16) {
            float4 av = *(const float4*)(A + (size_t)(m0 + lm) * 256 + k0 + lk);
            float4 bv = *(const float4*)(W + (size_t)(n0 + lm) * 256 + k0 + lk);
            As[lk + 0][lm] = av.x; As[lk + 1][lm] = av.y; As[lk + 2][lm] = av.z; As[lk + 3][lm] = av.w;
            Bs[lk + 0][lm] = bv.x; Bs[lk + 1][lm] = bv.y; Bs[lk + 2][lm] = bv.z; Bs[lk + 3][lm] = bv.w;
            __syncthreads();
#pragma unroll
            for (int kk = 0; kk < 16; ++kk) {
                float4 a4 = *(const float4*)&As[kk][ty << 2];
                float4 b4 = *(const float4*)&Bs[kk][tx << 2];
                float aa[4] = {a4.x, a4.y, a4.z, a4.w};
                float bb[4] = {b4.x, b4.y, b4.z, b4.w};
#pragma unroll
                for (int i = 0; i < 4; ++i)
#pragma unroll
                    for (int j = 0; j < 4; ++j)
                        acc[i][j] = fmaf(aa[i], bb[j], acc[i][j]);
            }
            __syncthreads();
        }
#pragma unroll
        for (int i = 0; i < 4; ++i) {
            const int m  = m0 + (ty << 2) + i;
            const int c0 = n0 + (tx << 2);
            float4 o = make_float4(acc[i][0] + bias[c0 + 0], acc[i][1] + bias[c0 + 1],
                                   acc[i][2] + bias[c0 + 2], acc[i][3] + bias[c0 + 3]);
            *(float4*)&C[(size_t)m * 256 + c0] = o;
        }
    }
}

extern "C" void kernel_launch(void* const* d_in, const int* in_sizes, int n_in,
                              void* d_out, int out_size, void* d_ws, size_t ws_size,
                              hipStream_t stream)
{
    const float* q  = (const float*)d_in[0];
    const float* k  = (const float*)d_in[1];
    const float* v  = (const float*)d_in[2];
    const float* Wi = (const float*)d_in[3];
    const float* bi = (const float*)d_in[4];
    const float* Wo = (const float*)d_in[5];
    const float* bo = (const float*)d_in[6];

    float* out      = (float*)d_out;
    float* attn_out = out;                 // [1024,4,256]
    float* cmask    = out + 1048576;       // [1024,1024]

    _Float16* Ppack    = (_Float16*)d_ws;
    float*    attn_pre = (float*)((char*)d_ws + 18874368);
    _Float16* pmask    = (_Float16*)((char*)d_ws + 23068672);
    _Float16* X16      = (_Float16*)((char*)d_ws + 90177536);
    _Float16* W16      = (_Float16*)((char*)d_ws + 96468992);

    cvt_kernel<<<1824, 256, 0, stream>>>(q, k, v, Wi, X16, W16);
    proj_kernel<<<dim3(36, 64), 256, 0, stream>>>(X16, W16, bi, Ppack);
    attn_kernel<<<2048, 512, 0, stream>>>(Ppack, attn_pre, pmask);
    tail_kernel<<<768, 256, 0, stream>>>(pmask, cmask, attn_pre, Wo, bo, attn_out);
}

// Round 6
// 260.654 us; speedup vs baseline: 1.1244x; 1.0617x over previous
//
#include <hip/hip_runtime.h>

// LearnableGlobalLocalMultiheadAttention — round 18.
// r17 post-mortem: register scan WIN (288.9 -> 276.7 total; attn ~146 us,
// matching the 135-145 prediction; rocprof durs inflated this round).
// r18 (attn phases 1/4/4b + tail index only; rest r17 verbatim):
// SWAPPED-OPERAND MFMA (mfma(B,A) => C^T; A/B fragment layouts are
// lane-symmetric for 16x16x32) so each thread owns (query row m16, 4
// CONSECUTIVE key cols jt*16+kg*4+i). This turns the mask phase from
// 256 scalar ds_read_u16/thread into aligned v4h reads:
//   - phase 1: 64 scalar LDS writes -> 16 v4h writes
//   - phase 4: PL/PR v4h; eLc/eRc from 1-shifted edge arrays Ledge/Redge
//     (written during scan from x[31]; [0]=0 kills the jr==0 select);
//     eLb/eRb 2 scalar; eLbc/eRbc 8 predicated scalar. ~14 vs 32 instrs/jt2.
//   - phase 4b: 32 scalar -> 8 v4h writes (free transpose back to
//     row-major S; phases 5/6/epilogue untouched).
//   - pmask fragment order becomes half = jt*256 + q*16 + c; tail T4
//     indexing adjusted (reduction is position-independent). T4 stride 136.
// LDS 66.0 -> 68.4 KB, still 2 blocks/CU. Predict: bank-conflict 917K ->
// ~0.5M, attn ~146 -> ~120-130, total ~250-262. absmax unchanged.
//
// Algorithmic core (verified r1-11): triu*mini = kron(triu32,triu32)
// =>  A @ triu   == 2D inclusive prefix-sum of each row viewed as [32][32]
//     A @ triu^T == suffix sum; after softmax the 2D total == 1.0 exactly.

typedef _Float16 v8h __attribute__((ext_vector_type(8)));
typedef _Float16 v4h __attribute__((ext_vector_type(4)));
typedef _Float16 v2h __attribute__((ext_vector_type(2)));
typedef float    v4f __attribute__((ext_vector_type(4)));

#define SL 1048576   // halves per packed slice (32 bh * 1024 * 32)
#define RS 1032      // LDS row stride in fp16 elems (1024 + 8 pad)

static constexpr float SCALE = 0.17677669529663687f; // 32^-0.5

// ws layout (bytes):
//   [0, 18874368)         : 9 packed fp16 slices, slice i at i*SL halves
//       q-type {0,3,5,7} / k-type {1,4,6,8}: [bh][tile(64)][lane(64)][8]
//       slice 2 (v), PV-B: [bh][kc(32)][nt(2)][lane(64)][8]
//   [18874368, +4 MB)     : attn_pre fp32 [4096][256]
//   [23068672, +64 MB)    : pmask fp16 [32][64 rt][16384] fragment order:
//                           half index = jt*256 + q*16 + c (r18 transposed)
//   [90177536, +6 MB)     : X16 fp16 {q,k,v} [4096][256] each
//   [96468992, +1.2 MB)   : W16 fp16 [2304][256]

// ---------------- Kernel 0: fp32 -> fp16 conversion (r12) ----------------
__global__ __launch_bounds__(256)
void cvt_kernel(const float* __restrict__ q, const float* __restrict__ k,
                const float* __restrict__ v, const float* __restrict__ W,
                _Float16* __restrict__ X16, _Float16* __restrict__ W16)
{
    const int b = blockIdx.x;
    const int t = threadIdx.x;
    const float* src; _Float16* dst; int off;
    if (b < 512)       { src = q; dst = X16;             off = b; }
    else if (b < 1024) { src = k; dst = X16 + (1 << 20); off = b - 512; }
    else if (b < 1536) { src = v; dst = X16 + (2 << 20); off = b - 1024; }
    else               { src = W; dst = W16;             off = b - 1536; }
    const int i = off * 2048 + t * 8;
    const float4 a = *(const float4*)(src + i);
    const float4 c = *(const float4*)(src + i + 4);
    v8h h;
    h[0] = (_Float16)a.x; h[1] = (_Float16)a.y; h[2] = (_Float16)a.z; h[3] = (_Float16)a.w;
    h[4] = (_Float16)c.x; h[5] = (_Float16)c.y; h[6] = (_Float16)c.z; h[7] = (_Float16)c.w;
    *(v8h*)(dst + i) = h;
}

// ---------------- Kernel 1: packed input projection (fp16 MFMA, r15) ----------------
__global__ __launch_bounds__(256)
void proj_kernel(const _Float16* __restrict__ X16, const _Float16* __restrict__ W16,
                 const float* __restrict__ bias, _Float16* __restrict__ P)
{
    __shared__ __align__(16) _Float16 stage[4096];   // 8 KB
    const int t  = threadIdx.x;
    const int n0 = blockIdx.x * 64;   // output column tile (0..2303)
    const int m0 = blockIdx.y * 64;   // row tile (0..4095), row = s*4 + b
    const int slice = n0 >> 8;        // uniform per block
    const int q2 = (n0 >> 6) & 3;     // 64-col quarter within slice
    const bool kslice = (slice == 1) || (slice == 4) || (slice == 6) || (slice == 8);
    const _Float16* X = X16 + (slice == 2 ? (2 << 20) : (kslice ? (1 << 20) : 0));
    const int w = t >> 6, lane = t & 63, m16 = lane & 15, kg = lane >> 4;
    const v4f zero = {0.f, 0.f, 0.f, 0.f};
    v4f acc[4] = {zero, zero, zero, zero};
    const _Float16* Arow = X + (size_t)(m0 + w * 16 + m16) * 256 + kg * 8;
    const _Float16* B0   = W16 + (size_t)(n0 + m16) * 256 + kg * 8;
#pragma unroll
    for (int kk = 0; kk < 8; ++kk) {
        const v8h a = *(const v8h*)(Arow + kk * 32);
#pragma unroll
        for (int nf = 0; nf < 4; ++nf) {
            const v8h bb = *(const v8h*)(B0 + nf * 4096 + kk * 32);
            acc[nf] = __builtin_amdgcn_mfma_f32_16x16x32_f16(a, bb, acc[nf], 0, 0, 0);
        }
    }
    const float scale = (slice == 0 || slice == 7) ? SCALE : 1.0f;
    // ---- stage into LDS with the packed-layout bijection ----
#pragma unroll
    for (int nf = 0; nf < 4; ++nf) {
        const int c = n0 + nf * 16 + m16;
        const float bv = bias[c];
#pragma unroll
        for (int i = 0; i < 4; ++i) {
            const _Float16 val = (_Float16)((acc[nf][i] + bv) * scale);
            const int lb = i * 2 + (nf >> 1);          // local bh 0..7
            int inner;
            if (slice == 2) {
                const int ls = w * 4 + kg;             // lm>>2 local row-quad
                inner = ((nf & 1) << 8) + ((ls >> 3) << 7) + m16 * 8 + (ls & 7);
            } else {
                inner = ((w * 4 + kg) + (((nf & 1) * 2 + (m16 >> 3)) << 4)) * 8 + (m16 & 7);
            }
            stage[lb * 512 + inner] = val;
        }
    }
    __syncthreads();
    // ---- coalesced copy-out: thread t -> 16 contiguous halves ----
    {
        const int o  = t * 16;
        const int lb = o >> 9;
        const int inner = o & 511;
        const int bs = lb >> 1, hh = lb & 1;
        const int bh = bs * 8 + 2 * q2 + hh;
        size_t dst;
        if (slice == 2) {
            const int kc = m0 >> 7;                    // s0>>5, constant per block
            const int g0 = (m0 >> 5) & 3;              // (s0>>3)&3, in {0,2}
            const int nt = inner >> 8, a = (inner >> 7) & 1, r = inner & 127;
            dst = (size_t)2 * SL + (size_t)bh * 32768
                + (size_t)(kc * 1024 + nt * 512 + (g0 + a) * 128 + r);
        } else {
            const int tile = m0 >> 6;
            dst = (size_t)slice * SL + (size_t)bh * 32768 + (size_t)(tile * 512 + inner);
        }
        *(v8h*)(P + dst)     = *(const v8h*)(stage + o);
        *(v8h*)(P + dst + 8) = *(const v8h*)(stage + o + 8);
    }
}

// ---------------- Kernel 2: fused MFMA attention (r18 swapped-MFMA) ----------------
// 2048 blocks x 512 threads (8 waves): xcd = bid&7, q = bid>>3;
// bh = xcd*4 + (q&3), rt = q>>2. (512,4): 16 waves/CU target.
__global__ __launch_bounds__(512, 4)
void attn_kernel(const _Float16* __restrict__ P, float* __restrict__ attn_pre,
                 _Float16* __restrict__ pmask)
{
    __shared__ __align__(16) _Float16 Lh[16 * RS];
    __shared__ __align__(16) _Float16 Rh[16 * RS];
    __shared__ __align__(16) _Float16 Ledge[16][36];   // [q][jr]: 0, S(31,jr-1)
    __shared__ __align__(16) _Float16 Redge[16][36];

    const int t    = threadIdx.x;
    const int bid  = blockIdx.x;
    const int q    = bid >> 3;
    const int bh   = ((bid & 7) << 2) + (q & 3);
    const int rt   = q >> 2;
    const int w    = __builtin_amdgcn_readfirstlane(t >> 6);
    const int lane = t & 63;
    const int m16  = lane & 15;
    const int kg   = lane >> 4;

    const _Float16* Pb = P + (size_t)bh * 32768;
    const v4f zero = {0.f, 0.f, 0.f, 0.f};

    // ---- Phase 1: left/right logits via SWAPPED MFMA -> row-major v4h writes ----
    // mfma(B,A) => thread (m16,kg) holds (query row m16, key cols jt*16+kg*4+i).
    {
        const v8h a_l = *(const v8h*)(Pb + 3 * SL + rt * 512 + lane * 8);
        const v8h a_r = *(const v8h*)(Pb + 5 * SL + rt * 512 + lane * 8);
        const _Float16* Bl = Pb + 4 * SL;
        const _Float16* Br = Pb + 6 * SL;
#pragma unroll 4
        for (int jt2 = 0; jt2 < 8; ++jt2) {
            const int jt = (w << 3) + jt2;
            const v8h bL = *(const v8h*)(Bl + jt * 512 + lane * 8);
            const v8h bR = *(const v8h*)(Br + jt * 512 + lane * 8);
            v4f cL = __builtin_amdgcn_mfma_f32_16x16x32_f16(bL, a_l, zero, 0, 0, 0);
            v4f cR = __builtin_amdgcn_mfma_f32_16x16x32_f16(bR, a_r, zero, 0, 0, 0);
            v4h hL, hR;
#pragma unroll
            for (int i = 0; i < 4; ++i) { hL[i] = (_Float16)cL[i]; hR[i] = (_Float16)cR[i]; }
            const int base = m16 * RS + (jt << 4) + (kg << 2);
            *(v4h*)&Lh[base] = hL;
            *(v4h*)&Rh[base] = hR;
        }
    }
    __syncthreads();

    // ---- Phase 2+3 fused: softmax + 2D inclusive scan, register-resident ----
    // lanes<32: L rows, lanes>=32: R rows; lane kr owns cols {kb*32+kr}.
    // Also writes the 1-shifted suffix-edge arrays from x[31].
    {
        const int kr = lane & 31;
        for (int r = 0; r < 2; ++r) {
            const int row = (w << 1) + r;
            _Float16* ROW = (lane >= 32) ? &Rh[row * RS] : &Lh[row * RS];
            float x[32];
#pragma unroll
            for (int kb = 0; kb < 32; ++kb)
                x[kb] = __expf((float)ROW[(kb << 5) + kr]);
#pragma unroll
            for (int kb = 0; kb < 32; ++kb) {
#pragma unroll
                for (int off = 1; off < 32; off <<= 1) {
                    const float y = __shfl_up(x[kb], off, 32);
                    if (kr >= off) x[kb] += y;
                }
            }
#pragma unroll
            for (int kb = 1; kb < 32; ++kb) x[kb] += x[kb - 1];
            const float inv = 1.f / __shfl(x[31], 31, 32);
            _Float16* EG = (lane >= 32) ? &Redge[row][0] : &Ledge[row][0];
            EG[kr + 1] = (_Float16)(x[31] * inv);
            if (kr == 0) EG[0] = (_Float16)0.f;
#pragma unroll
            for (int kb = 0; kb < 32; ++kb)
                ROW[(kb << 5) + kr] = (_Float16)(x[kb] * inv);
        }
    }
    __syncthreads();

    // ---- Phase 4: single pass, FULL unroll, SWAPPED MFMA + v4h mask reads;
    // mk -> pmask direct (half = jt*256 + q*16 + c); sc4 sole carry. ----
    v4h sc4[8];
    {
        _Float16* pm = pmask + (size_t)bh * 1048576 + (size_t)rt * 16384;
        const v8h a_g = *(const v8h*)(Pb + 0 * SL + rt * 512 + lane * 8);
        const v8h a_c = *(const v8h*)(Pb + 7 * SL + rt * 512 + lane * 8);
        const _Float16* Bg = Pb + 1 * SL;
        const _Float16* Bc = Pb + 8 * SL;
        const int rr = m16 * RS;
#pragma unroll
        for (int jt2 = 0; jt2 < 8; ++jt2) {
            const int jt   = (w << 3) + jt2;
            const int jb   = jt >> 1;
            const int jr0  = ((jt & 1) << 4) + (kg << 2);
            const int colb = (jt << 4) + (kg << 2);
            const v8h bG = *(const v8h*)(Bg + jt * 512 + lane * 8);
            const v8h bC = *(const v8h*)(Bc + jt * 512 + lane * 8);
            const v4f g4 = __builtin_amdgcn_mfma_f32_16x16x32_f16(bG, a_g, zero, 0, 0, 0);
            const v4f l4 = __builtin_amdgcn_mfma_f32_16x16x32_f16(bC, a_c, zero, 0, 0, 0);
            const v4h PLv  = *(const v4h*)&Lh[rr + colb];
            const v4h PRv  = *(const v4h*)&Rh[rr + colb];
            const v4h eLcv = *(const v4h*)&Ledge[m16][jr0];
            const v4h eRcv = *(const v4h*)&Redge[m16][jr0];
            float eLb = 0.f, eRb = 0.f;
            if (jb) {
                eLb = (float)Lh[rr + (jb << 5) - 1];
                eRb = (float)Rh[rr + (jb << 5) - 1];
            }
            v4h s4, m4;
#pragma unroll
            for (int i = 0; i < 4; ++i) {
                const int jrv = jr0 + i;
                const float PL  = (float)PLv[i];
                const float PR  = (float)PRv[i];
                const float eLc = (float)eLcv[i];
                const float eRc = (float)eRcv[i];
                float eLbc = 0.f, eRbc = 0.f;
                if (jb && jrv) {
                    const int o = rr + ((jb - 1) << 5) + jrv - 1;
                    eLbc = (float)Lh[o];
                    eRbc = (float)Rh[o];
                }
                const float SLv = 1.0f - eLb - eLc + eLbc;
                const float SRv = 1.0f - eRb - eRc + eRbc;
                const float mkv = PL * SRv + SLv * PR;
                s4[i] = (_Float16)(0.1f * g4[i] + l4[i] * mkv);
                m4[i] = (_Float16)mkv;
            }
            sc4[jt2] = s4;
            *(v4h*)(pm + ((size_t)jt << 8) + (m16 << 4) + (kg << 2)) = m4;
        }
    }
    __syncthreads();   // all scan reads complete before overwrite

    // ---- Phase 4b: write S -> Lh (v4h, free transpose to row-major) ----
    {
#pragma unroll
        for (int jt2 = 0; jt2 < 8; ++jt2)
            *(v4h*)&Lh[m16 * RS + (((w << 3) + jt2) << 4) + (kg << 2)] = sc4[jt2];
    }
    __syncthreads();

    // ---- Phase 5: final softmax on S ----
    auto softmax_pairs = [&](_Float16* ROW) {
        float v0[8], v1[8];
        float ss = 0.f;
#pragma unroll
        for (int kq = 0; kq < 8; ++kq) {
            const v2h pr = *(const v2h*)&ROW[(lane + (kq << 6)) << 1];
            v0[kq] = __expf((float)pr[0]);
            v1[kq] = __expf((float)pr[1]);
            ss += v0[kq] + v1[kq];
        }
#pragma unroll
        for (int off = 32; off; off >>= 1) ss += __shfl_xor(ss, off);
        const float inv = 1.f / ss;
#pragma unroll
        for (int kq = 0; kq < 8; ++kq) {
            v2h pr; pr[0] = (_Float16)(v0[kq] * inv); pr[1] = (_Float16)(v1[kq] * inv);
            *(v2h*)&ROW[(lane + (kq << 6)) << 1] = pr;
        }
    };
#pragma unroll
    for (int r = 0; r < 2; ++r) softmax_pairs(&Lh[((w << 1) + r) * RS]);
    __syncthreads();

    // ---- Phase 6: PV via MFMA. wave = (nt = d-half, hf = j-quarter) ----
    {
        const int nt = w & 1, hf = w >> 1;
        v4f c = zero;
        const _Float16* Vb = Pb + 2 * SL + nt * 512 + lane * 8;
        const int kc0 = hf << 3;
#pragma unroll 4
        for (int kc2 = 0; kc2 < 8; ++kc2) {
            const int kc = kc0 + kc2;
            const v8h a = *(const v8h*)&Lh[m16 * RS + (kc << 5) + (kg << 3)];
            const v8h b = *(const v8h*)(Vb + (size_t)kc * 1024);
            c = __builtin_amdgcn_mfma_f32_16x16x32_f16(a, b, c, 0, 0, 0);
        }
        float* Pbuf = (float*)&Rh[0];   // Rh dead since phase-4 barrier
#pragma unroll
        for (int i = 0; i < 4; ++i) Pbuf[(w << 8) + (lane << 2) + i] = c[i];
    }
    __syncthreads();

    // ---- Epilogue: fold 4 j-quarters, coalesced d-fastest store ----
    {
        const float* Pbuf = (const float*)&Rh[0];
        const int r   = t >> 5;                    // row in tile (0..15)
        const int d   = t & 31;
        const int nt2 = d >> 4, n = d & 15;
        const int kg2 = r >> 2, i2 = r & 3;
        const int off = (kg2 << 6) + (n << 2) + i2;   // lane*4 + i
        float v = 0.f;
#pragma unroll
        for (int hf = 0; hf < 4; ++hf)
            v += Pbuf[(((hf << 1) + nt2) << 8) + off];
        const int srow = (rt << 4) + r;
        attn_pre[((size_t)(srow * 4 + (bh >> 3))) * 256 + (bh & 7) * 32 + d] = v;
    }
}

// ---------------- Kernel 3: fused tail — outproj (blocks 0..255) + cmask (256..767) ----
// r18: pmask fragment order is half = jt*256 + q*16 + c; T4 index adjusted,
// stride padded to 136 for write-bank spread.
__global__ __launch_bounds__(256)
void tail_kernel(const _Float16* __restrict__ pmask, float* __restrict__ cmask,
                 const float* __restrict__ A, const float* __restrict__ W,
                 const float* __restrict__ bias, float* __restrict__ C)
{
    __shared__ __align__(16) float SMEM[4 * 16 * 136];   // 34816 B
    const int bid = blockIdx.x;
    const int t = threadIdx.x;

    if (bid >= 256) {
        // ---- cmask part: 512 blocks, grid-equivalent (64 rt, 8 wh) ----
        const int b2 = bid - 256;
        const int rt = b2 >> 3, wh = b2 & 7;
        float (*T4)[16][136] = (float(*)[16][136])SMEM;
        const int wv = t >> 6;                            // wave -> bh octet
        const int lane = t & 63;
        float acc[8][4] = {};
        const _Float16* base = pmask + (size_t)rt * 16384 + ((size_t)wh << 11) + (lane << 2)
                             + ((size_t)wv << 3) * 1048576;
        for (int bh = 0; bh < 8; ++bh) {
            const _Float16* p = base + (size_t)bh * 1048576;
#pragma unroll
            for (int jt2 = 0; jt2 < 8; ++jt2) {
                const v4h h4 = *(const v4h*)(p + (jt2 << 8));
#pragma unroll
                for (int i = 0; i < 4; ++i) acc[jt2][i] += (float)h4[i];
            }
        }
        // half index e = lane*4+i = q*16 + c  ->  q = lane>>2, c = (lane&3)*4+i
#pragma unroll
        for (int jt2 = 0; jt2 < 8; ++jt2)
#pragma unroll
            for (int i = 0; i < 4; ++i)
                T4[wv][lane >> 2][(jt2 << 4) + ((lane & 3) << 2) + i] = acc[jt2][i];
        __syncthreads();
        // 16 rows x 128 cols; thread t -> row t>>4, 8 consecutive cols.
        const int row = t >> 4;
        const int c0  = (t & 15) << 3;
#pragma unroll
        for (int h = 0; h < 2; ++h) {
            const int c = c0 + (h << 2);
            const float4 s0 = *(const float4*)&T4[0][row][c];
            const float4 s1 = *(const float4*)&T4[1][row][c];
            const float4 s2 = *(const float4*)&T4[2][row][c];
            const float4 s3 = *(const float4*)&T4[3][row][c];
            const float4 o = make_float4(s0.x + s1.x + s2.x + s3.x,
                                         s0.y + s1.y + s2.y + s3.y,
                                         s0.z + s1.z + s2.z + s3.z,
                                         s0.w + s1.w + s2.w + s3.w);
            *(float4*)&cmask[((size_t)((rt << 4) + row) << 10) + (wh << 7) + c] = o;
        }
    } else {
        // ---- outproj part: 256 blocks, grid-equivalent (4 n0, 64 m0) ----
        const int n0 = (bid & 3) * 64;
        const int m0 = (bid >> 2) * 64;
        float (*As)[68] = (float(*)[68])SMEM;
        float (*Bs)[68] = (float(*)[68])(SMEM + 16 * 68);
        const int tx = t & 15, ty = t >> 4;
        const int lm = t >> 2, lk = (t & 3) << 2;
        float acc[4][4] = {};
        for (int k0 = 0; k0 < 256; k0 += 16) {
            float4 av = *(const float4*)(A + (size_t)(m0 + lm) * 256 + k0 + lk);
            float4 bv = *(const float4*)(W + (size_t)(n0 + lm) * 256 + k0 + lk);
            As[lk + 0][lm] = av.x; As[lk + 1][lm] = av.y; As[lk + 2][lm] = av.z; As[lk + 3][lm] = av.w;
            Bs[lk + 0][lm] = bv.x; Bs[lk + 1][lm] = bv.y; Bs[lk + 2][lm] = bv.z; Bs[lk + 3][lm] = bv.w;
            __syncthreads();
#pragma unroll
            for (int kk = 0; kk < 16; ++kk) {
                float4 a4 = *(const float4*)&As[kk][ty << 2];
                float4 b4 = *(const float4*)&Bs[kk][tx << 2];
                float aa[4] = {a4.x, a4.y, a4.z, a4.w};
                float bb[4] = {b4.x, b4.y, b4.z, b4.w};
#pragma unroll
                for (int i = 0; i < 4; ++i)
#pragma unroll
                    for (int j = 0; j < 4; ++j)
                        acc[i][j] = fmaf(aa[i], bb[j], acc[i][j]);
            }
            __syncthreads();
        }
#pragma unroll
        for (int i = 0; i < 4; ++i) {
            const int m  = m0 + (ty << 2) + i;
            const int c0 = n0 + (tx << 2);
            float4 o = make_float4(acc[i][0] + bias[c0 + 0], acc[i][1] + bias[c0 + 1],
                                   acc[i][2] + bias[c0 + 2], acc[i][3] + bias[c0 + 3]);
            *(float4*)&C[(size_t)m * 256 + c0] = o;
        }
    }
}

extern "C" void kernel_launch(void* const* d_in, const int* in_sizes, int n_in,
                              void* d_out, int out_size, void* d_ws, size_t ws_size,
                              hipStream_t stream)
{
    const float* q  = (const float*)d_in[0];
    const float* k  = (const float*)d_in[1];
    const float* v  = (const float*)d_in[2];
    const float* Wi = (const float*)d_in[3];
    const float* bi = (const float*)d_in[4];
    const float* Wo = (const float*)d_in[5];
    const float* bo = (const float*)d_in[6];

    float* out      = (float*)d_out;
    float* attn_out = out;                 // [1024,4,256]
    float* cmask    = out + 1048576;       // [1024,1024]

    _Float16* Ppack    = (_Float16*)d_ws;
    float*    attn_pre = (float*)((char*)d_ws + 18874368);
    _Float16* pmask    = (_Float16*)((char*)d_ws + 23068672);
    _Float16* X16      = (_Float16*)((char*)d_ws + 90177536);
    _Float16* W16      = (_Float16*)((char*)d_ws + 96468992);

    cvt_kernel<<<1824, 256, 0, stream>>>(q, k, v, Wi, X16, W16);
    proj_kernel<<<dim3(36, 64), 256, 0, stream>>>(X16, W16, bi, Ppack);
    attn_kernel<<<2048, 512, 0, stream>>>(Ppack, attn_pre, pmask);
    tail_kernel<<<768, 256, 0, stream>>>(pmask, cmask, attn_pre, Wo, bo, attn_out);
}

// Round 7
// 257.013 us; speedup vs baseline: 1.1403x; 1.0142x over previous
//
#include <hip/hip_runtime.h>

// LearnableGlobalLocalMultiheadAttention — round 19.
// r18 post-mortem: swapped-MFMA WIN (attn 146->132.4, total 276.7->260.7;
// spills also fell: FETCH 86->36, WRITE 200->123 MB).
// r19 changes:
//  1. attn: DELETE phase 5. Phase 4 computes p=exp(s) in f32, keeps fp16 p4
//     regs, per-thread row-partial sum -> shfl_xor(16,32) over kg-lanes ->
//     Zp[8][16] LDS; after the (already-needed) barrier each thread sums 8
//     floats -> inv, writes normalized S~ directly to Lh (replaces ph4b).
//     Barriers 5 -> 4. Numerics: exp on f32 s (was fp16-rounded) — tighter.
//  2. proj: 128-col tiles (grid 18x64, acc[8]) — halves A-tile re-read
//     traffic (36 -> 18 n-blocks over the 6 MB X16) and block count.
//
// Algorithmic core (verified r1-11): triu*mini = kron(triu32,triu32)
// =>  A @ triu   == 2D inclusive prefix-sum of each row viewed as [32][32]
//     A @ triu^T == suffix sum; after softmax the 2D total == 1.0 exactly.

typedef _Float16 v8h __attribute__((ext_vector_type(8)));
typedef _Float16 v4h __attribute__((ext_vector_type(4)));
typedef _Float16 v2h __attribute__((ext_vector_type(2)));
typedef float    v4f __attribute__((ext_vector_type(4)));

#define SL 1048576   // halves per packed slice (32 bh * 1024 * 32)
#define RS 1032      // LDS row stride in fp16 elems (1024 + 8 pad)

static constexpr float SCALE = 0.17677669529663687f; // 32^-0.5

// ws layout (bytes):
//   [0, 18874368)         : 9 packed fp16 slices, slice i at i*SL halves
//       q-type {0,3,5,7} / k-type {1,4,6,8}: [bh][tile(64)][lane(64)][8]
//       slice 2 (v), PV-B: [bh][kc(32)][nt(2)][lane(64)][8]
//   [18874368, +4 MB)     : attn_pre fp32 [4096][256]
//   [23068672, +64 MB)    : pmask fp16 [32][64 rt][16384] fragment order:
//                           half index = jt*256 + q*16 + c (r18 transposed)
//   [90177536, +6 MB)     : X16 fp16 {q,k,v} [4096][256] each
//   [96468992, +1.2 MB)   : W16 fp16 [2304][256]

// ---------------- Kernel 0: fp32 -> fp16 conversion (r12) ----------------
__global__ __launch_bounds__(256)
void cvt_kernel(const float* __restrict__ q, const float* __restrict__ k,
                const float* __restrict__ v, const float* __restrict__ W,
                _Float16* __restrict__ X16, _Float16* __restrict__ W16)
{
    const int b = blockIdx.x;
    const int t = threadIdx.x;
    const float* src; _Float16* dst; int off;
    if (b < 512)       { src = q; dst = X16;             off = b; }
    else if (b < 1024) { src = k; dst = X16 + (1 << 20); off = b - 512; }
    else if (b < 1536) { src = v; dst = X16 + (2 << 20); off = b - 1024; }
    else               { src = W; dst = W16;             off = b - 1536; }
    const int i = off * 2048 + t * 8;
    const float4 a = *(const float4*)(src + i);
    const float4 c = *(const float4*)(src + i + 4);
    v8h h;
    h[0] = (_Float16)a.x; h[1] = (_Float16)a.y; h[2] = (_Float16)a.z; h[3] = (_Float16)a.w;
    h[4] = (_Float16)c.x; h[5] = (_Float16)c.y; h[6] = (_Float16)c.z; h[7] = (_Float16)c.w;
    *(v8h*)(dst + i) = h;
}

// ---------------- Kernel 1: packed input projection (r19: 128-col tiles) ----------------
__global__ __launch_bounds__(256)
void proj_kernel(const _Float16* __restrict__ X16, const _Float16* __restrict__ W16,
                 const float* __restrict__ bias, _Float16* __restrict__ P)
{
    __shared__ __align__(16) _Float16 stage[8192];   // 16 KB
    const int t  = threadIdx.x;
    const int n0 = blockIdx.x * 128;  // output column tile (0..2303)
    const int m0 = blockIdx.y * 64;   // row tile (0..4095), row = s*4 + b
    const int slice = n0 >> 8;        // uniform per block
    const int q4 = (n0 >> 7) & 1;     // 128-col half within slice
    const bool kslice = (slice == 1) || (slice == 4) || (slice == 6) || (slice == 8);
    const _Float16* X = X16 + (slice == 2 ? (2 << 20) : (kslice ? (1 << 20) : 0));
    const int w = t >> 6, lane = t & 63, m16 = lane & 15, kg = lane >> 4;
    const v4f zero = {0.f, 0.f, 0.f, 0.f};
    v4f acc[8] = {zero, zero, zero, zero, zero, zero, zero, zero};
    const _Float16* Arow = X + (size_t)(m0 + w * 16 + m16) * 256 + kg * 8;
    const _Float16* B0   = W16 + (size_t)(n0 + m16) * 256 + kg * 8;
#pragma unroll
    for (int kk = 0; kk < 8; ++kk) {
        const v8h a = *(const v8h*)(Arow + kk * 32);
#pragma unroll
        for (int nf = 0; nf < 8; ++nf) {
            const v8h bb = *(const v8h*)(B0 + nf * 4096 + kk * 32);
            acc[nf] = __builtin_amdgcn_mfma_f32_16x16x32_f16(a, bb, acc[nf], 0, 0, 0);
        }
    }
    const float scale = (slice == 0 || slice == 7) ? SCALE : 1.0f;
    // ---- stage into LDS with the packed-layout bijection ----
#pragma unroll
    for (int nf = 0; nf < 8; ++nf) {
        const int c = n0 + nf * 16 + m16;
        const float bv = bias[c];
#pragma unroll
        for (int i = 0; i < 4; ++i) {
            const _Float16 val = (_Float16)((acc[nf][i] + bv) * scale);
            const int lb = i * 4 + (nf >> 1);          // local bh 0..15
            int inner;
            if (slice == 2) {
                const int ls = w * 4 + kg;             // local row-quad
                inner = ((nf & 1) << 8) + ((ls >> 3) << 7) + m16 * 8 + (ls & 7);
            } else {
                inner = ((w * 4 + kg) + (((nf & 1) * 2 + (m16 >> 3)) << 4)) * 8 + (m16 & 7);
            }
            stage[lb * 512 + inner] = val;
        }
    }
    __syncthreads();
    // ---- coalesced copy-out: thread t -> 32 contiguous halves ----
    {
        const int o  = t * 32;
        const int lb = o >> 9;
        const int inner = o & 511;
        const int bs = lb >> 2, hh = lb & 3;
        const int bh = bs * 8 + q4 * 4 + hh;
        size_t dst;
        if (slice == 2) {
            const int kc = m0 >> 7;                    // s0>>5, constant per block
            const int g0 = (m0 >> 5) & 3;              // (s0>>3)&3, in {0,2}
            const int nt = inner >> 8, a2 = (inner >> 7) & 1, r = inner & 127;
            dst = (size_t)2 * SL + (size_t)bh * 32768
                + (size_t)(kc * 1024 + nt * 512 + (g0 + a2) * 128 + r);
        } else {
            const int tile = m0 >> 6;
            dst = (size_t)slice * SL + (size_t)bh * 32768 + (size_t)(tile * 512 + inner);
        }
#pragma unroll
        for (int h8 = 0; h8 < 4; ++h8)
            *(v8h*)(P + dst + h8 * 8) = *(const v8h*)(stage + o + h8 * 8);
    }
}

// ---------------- Kernel 2: fused MFMA attention (r19: ph4b/5 merged into ph4) ----------------
// 2048 blocks x 512 threads (8 waves): xcd = bid&7, q = bid>>3;
// bh = xcd*4 + (q&3), rt = q>>2. (512,4): 16 waves/CU target. 4 barriers.
__global__ __launch_bounds__(512, 4)
void attn_kernel(const _Float16* __restrict__ P, float* __restrict__ attn_pre,
                 _Float16* __restrict__ pmask)
{
    __shared__ __align__(16) _Float16 Lh[16 * RS];
    __shared__ __align__(16) _Float16 Rh[16 * RS];
    __shared__ __align__(16) _Float16 Ledge[16][36];   // [q][jr]: 0, S(31,jr-1)
    __shared__ __align__(16) _Float16 Redge[16][36];
    __shared__ float Zp[8][16];                        // per-wave row sums

    const int t    = threadIdx.x;
    const int bid  = blockIdx.x;
    const int q    = bid >> 3;
    const int bh   = ((bid & 7) << 2) + (q & 3);
    const int rt   = q >> 2;
    const int w    = __builtin_amdgcn_readfirstlane(t >> 6);
    const int lane = t & 63;
    const int m16  = lane & 15;
    const int kg   = lane >> 4;

    const _Float16* Pb = P + (size_t)bh * 32768;
    const v4f zero = {0.f, 0.f, 0.f, 0.f};

    // ---- Phase 1: left/right logits via SWAPPED MFMA -> row-major v4h writes ----
    {
        const v8h a_l = *(const v8h*)(Pb + 3 * SL + rt * 512 + lane * 8);
        const v8h a_r = *(const v8h*)(Pb + 5 * SL + rt * 512 + lane * 8);
        const _Float16* Bl = Pb + 4 * SL;
        const _Float16* Br = Pb + 6 * SL;
#pragma unroll 4
        for (int jt2 = 0; jt2 < 8; ++jt2) {
            const int jt = (w << 3) + jt2;
            const v8h bL = *(const v8h*)(Bl + jt * 512 + lane * 8);
            const v8h bR = *(const v8h*)(Br + jt * 512 + lane * 8);
            v4f cL = __builtin_amdgcn_mfma_f32_16x16x32_f16(bL, a_l, zero, 0, 0, 0);
            v4f cR = __builtin_amdgcn_mfma_f32_16x16x32_f16(bR, a_r, zero, 0, 0, 0);
            v4h hL, hR;
#pragma unroll
            for (int i = 0; i < 4; ++i) { hL[i] = (_Float16)cL[i]; hR[i] = (_Float16)cR[i]; }
            const int base = m16 * RS + (jt << 4) + (kg << 2);
            *(v4h*)&Lh[base] = hL;
            *(v4h*)&Rh[base] = hR;
        }
    }
    __syncthreads();

    // ---- Phase 2+3 fused: softmax + 2D inclusive scan, register-resident ----
    {
        const int kr = lane & 31;
        for (int r = 0; r < 2; ++r) {
            const int row = (w << 1) + r;
            _Float16* ROW = (lane >= 32) ? &Rh[row * RS] : &Lh[row * RS];
            float x[32];
#pragma unroll
            for (int kb = 0; kb < 32; ++kb)
                x[kb] = __expf((float)ROW[(kb << 5) + kr]);
#pragma unroll
            for (int kb = 0; kb < 32; ++kb) {
#pragma unroll
                for (int off = 1; off < 32; off <<= 1) {
                    const float y = __shfl_up(x[kb], off, 32);
                    if (kr >= off) x[kb] += y;
                }
            }
#pragma unroll
            for (int kb = 1; kb < 32; ++kb) x[kb] += x[kb - 1];
            const float inv = 1.f / __shfl(x[31], 31, 32);
            _Float16* EG = (lane >= 32) ? &Redge[row][0] : &Ledge[row][0];
            EG[kr + 1] = (_Float16)(x[31] * inv);
            if (kr == 0) EG[0] = (_Float16)0.f;
#pragma unroll
            for (int kb = 0; kb < 32; ++kb)
                ROW[(kb << 5) + kr] = (_Float16)(x[kb] * inv);
        }
    }
    __syncthreads();

    // ---- Phase 4: logits + mask + EXP + row-sum; mk -> pmask; p4 carry ----
    v4h p4[8];
    float psum = 0.f;
    {
        _Float16* pm = pmask + (size_t)bh * 1048576 + (size_t)rt * 16384;
        const v8h a_g = *(const v8h*)(Pb + 0 * SL + rt * 512 + lane * 8);
        const v8h a_c = *(const v8h*)(Pb + 7 * SL + rt * 512 + lane * 8);
        const _Float16* Bg = Pb + 1 * SL;
        const _Float16* Bc = Pb + 8 * SL;
        const int rr = m16 * RS;
#pragma unroll
        for (int jt2 = 0; jt2 < 8; ++jt2) {
            const int jt   = (w << 3) + jt2;
            const int jb   = jt >> 1;
            const int jr0  = ((jt & 1) << 4) + (kg << 2);
            const int colb = (jt << 4) + (kg << 2);
            const v8h bG = *(const v8h*)(Bg + jt * 512 + lane * 8);
            const v8h bC = *(const v8h*)(Bc + jt * 512 + lane * 8);
            const v4f g4 = __builtin_amdgcn_mfma_f32_16x16x32_f16(bG, a_g, zero, 0, 0, 0);
            const v4f l4 = __builtin_amdgcn_mfma_f32_16x16x32_f16(bC, a_c, zero, 0, 0, 0);
            const v4h PLv  = *(const v4h*)&Lh[rr + colb];
            const v4h PRv  = *(const v4h*)&Rh[rr + colb];
            const v4h eLcv = *(const v4h*)&Ledge[m16][jr0];
            const v4h eRcv = *(const v4h*)&Redge[m16][jr0];
            float eLb = 0.f, eRb = 0.f;
            if (jb) {
                eLb = (float)Lh[rr + (jb << 5) - 1];
                eRb = (float)Rh[rr + (jb << 5) - 1];
            }
            v4h m4;
#pragma unroll
            for (int i = 0; i < 4; ++i) {
                const int jrv = jr0 + i;
                const float PL  = (float)PLv[i];
                const float PR  = (float)PRv[i];
                const float eLc = (float)eLcv[i];
                const float eRc = (float)eRcv[i];
                float eLbc = 0.f, eRbc = 0.f;
                if (jb && jrv) {
                    const int o = rr + ((jb - 1) << 5) + jrv - 1;
                    eLbc = (float)Lh[o];
                    eRbc = (float)Rh[o];
                }
                const float SLv = 1.0f - eLb - eLc + eLbc;
                const float SRv = 1.0f - eRb - eRc + eRbc;
                const float mkv = PL * SRv + SLv * PR;
                const float pv  = __expf(0.1f * g4[i] + l4[i] * mkv);
                p4[jt2][i] = (_Float16)pv;
                psum += pv;
                m4[i] = (_Float16)mkv;
            }
            *(v4h*)(pm + ((size_t)jt << 8) + (m16 << 4) + (kg << 2)) = m4;
        }
        // reduce partial sum over the 4 kg-lanes sharing row m16
        psum += __shfl_xor(psum, 16);
        psum += __shfl_xor(psum, 32);
        if (lane < 16) Zp[w][m16] = psum;
    }
    __syncthreads();   // scan reads done + Zp published

    // ---- Phase 4b': cross-wave denominator + normalized S~ write ----
    {
        float Z = 0.f;
#pragma unroll
        for (int w8 = 0; w8 < 8; ++w8) Z += Zp[w8][m16];
        const float inv = 1.f / Z;
#pragma unroll
        for (int jt2 = 0; jt2 < 8; ++jt2) {
            v4h o;
#pragma unroll
            for (int i = 0; i < 4; ++i) o[i] = (_Float16)((float)p4[jt2][i] * inv);
            *(v4h*)&Lh[m16 * RS + (((w << 3) + jt2) << 4) + (kg << 2)] = o;
        }
    }
    __syncthreads();

    // ---- Phase 6: PV via MFMA. wave = (nt = d-half, hf = j-quarter) ----
    {
        const int nt = w & 1, hf = w >> 1;
        v4f c = zero;
        const _Float16* Vb = Pb + 2 * SL + nt * 512 + lane * 8;
        const int kc0 = hf << 3;
#pragma unroll 4
        for (int kc2 = 0; kc2 < 8; ++kc2) {
            const int kc = kc0 + kc2;
            const v8h a = *(const v8h*)&Lh[m16 * RS + (kc << 5) + (kg << 3)];
            const v8h b = *(const v8h*)(Vb + (size_t)kc * 1024);
            c = __builtin_amdgcn_mfma_f32_16x16x32_f16(a, b, c, 0, 0, 0);
        }
        float* Pbuf = (float*)&Rh[0];   // Rh dead since phase-4 barrier
#pragma unroll
        for (int i = 0; i < 4; ++i) Pbuf[(w << 8) + (lane << 2) + i] = c[i];
    }
    __syncthreads();

    // ---- Epilogue: fold 4 j-quarters, coalesced d-fastest store ----
    {
        const float* Pbuf = (const float*)&Rh[0];
        const int r   = t >> 5;                    // row in tile (0..15)
        const int d   = t & 31;
        const int nt2 = d >> 4, n = d & 15;
        const int kg2 = r >> 2, i2 = r & 3;
        const int off = (kg2 << 6) + (n << 2) + i2;   // lane*4 + i
        float v = 0.f;
#pragma unroll
        for (int hf = 0; hf < 4; ++hf)
            v += Pbuf[(((hf << 1) + nt2) << 8) + off];
        const int srow = (rt << 4) + r;
        attn_pre[((size_t)(srow * 4 + (bh >> 3))) * 256 + (bh & 7) * 32 + d] = v;
    }
}

// ---------------- Kernel 3: fused tail — outproj (blocks 0..255) + cmask (256..767) ----
__global__ __launch_bounds__(256)
void tail_kernel(const _Float16* __restrict__ pmask, float* __restrict__ cmask,
                 const float* __restrict__ A, const float* __restrict__ W,
                 const float* __restrict__ bias, float* __restrict__ C)
{
    __shared__ __align__(16) float SMEM[4 * 16 * 136];   // 34816 B
    const int bid = blockIdx.x;
    const int t = threadIdx.x;

    if (bid >= 256) {
        // ---- cmask part: 512 blocks, grid-equivalent (64 rt, 8 wh) ----
        const int b2 = bid - 256;
        const int rt = b2 >> 3, wh = b2 & 7;
        float (*T4)[16][136] = (float(*)[16][136])SMEM;
        const int wv = t >> 6;                            // wave -> bh octet
        const int lane = t & 63;
        float acc[8][4] = {};
        const _Float16* base = pmask + (size_t)rt * 16384 + ((size_t)wh << 11) + (lane << 2)
                             + ((size_t)wv << 3) * 1048576;
        for (int bh = 0; bh < 8; ++bh) {
            const _Float16* p = base + (size_t)bh * 1048576;
#pragma unroll
            for (int jt2 = 0; jt2 < 8; ++jt2) {
                const v4h h4 = *(const v4h*)(p + (jt2 << 8));
#pragma unroll
                for (int i = 0; i < 4; ++i) acc[jt2][i] += (float)h4[i];
            }
        }
        // half index e = lane*4+i = q*16 + c  ->  q = lane>>2, c = (lane&3)*4+i
#pragma unroll
        for (int jt2 = 0; jt2 < 8; ++jt2)
#pragma unroll
            for (int i = 0; i < 4; ++i)
                T4[wv][lane >> 2][(jt2 << 4) + ((lane & 3) << 2) + i] = acc[jt2][i];
        __syncthreads();
        // 16 rows x 128 cols; thread t -> row t>>4, 8 consecutive cols.
        const int row = t >> 4;
        const int c0  = (t & 15) << 3;
#pragma unroll
        for (int h = 0; h < 2; ++h) {
            const int c = c0 + (h << 2);
            const float4 s0 = *(const float4*)&T4[0][row][c];
            const float4 s1 = *(const float4*)&T4[1][row][c];
            const float4 s2 = *(const float4*)&T4[2][row][c];
            const float4 s3 = *(const float4*)&T4[3][row][c];
            const float4 o = make_float4(s0.x + s1.x + s2.x + s3.x,
                                         s0.y + s1.y + s2.y + s3.y,
                                         s0.z + s1.z + s2.z + s3.z,
                                         s0.w + s1.w + s2.w + s3.w);
            *(float4*)&cmask[((size_t)((rt << 4) + row) << 10) + (wh << 7) + c] = o;
        }
    } else {
        // ---- outproj part: 256 blocks, grid-equivalent (4 n0, 64 m0) ----
        const int n0 = (bid & 3) * 64;
        const int m0 = (bid >> 2) * 64;
        float (*As)[68] = (float(*)[68])SMEM;
        float (*Bs)[68] = (float(*)[68])(SMEM + 16 * 68);
        const int tx = t & 15, ty = t >> 4;
        const int lm = t >> 2, lk = (t & 3) << 2;
        float acc[4][4] = {};
        for (int k0 = 0; k0 < 256; k0 += 16) {
            float4 av = *(const float4*)(A + (size_t)(m0 + lm) * 256 + k0 + lk);
            float4 bv = *(const float4*)(W + (size_t)(n0 + lm) * 256 + k0 + lk);
            As[lk + 0][lm] = av.x; As[lk + 1][lm] = av.y; As[lk + 2][lm] = av.z; As[lk + 3][lm] = av.w;
            Bs[lk + 0][lm] = bv.x; Bs[lk + 1][lm] = bv.y; Bs[lk + 2][lm] = bv.z; Bs[lk + 3][lm] = bv.w;
            __syncthreads();
#pragma unroll
            for (int kk = 0; kk < 16; ++kk) {
                float4 a4 = *(const float4*)&As[kk][ty << 2];
                float4 b4 = *(const float4*)&Bs[kk][tx << 2];
                float aa[4] = {a4.x, a4.y, a4.z, a4.w};
                float bb[4] = {b4.x, b4.y, b4.z, b4.w};
#pragma unroll
                for (int i = 0; i < 4; ++i)
#pragma unroll
                    for (int j = 0; j < 4; ++j)
                        acc[i][j] = fmaf(aa[i], bb[j], acc[i][j]);
            }
            __syncthreads();
        }
#pragma unroll
        for (int i = 0; i < 4; ++i) {
            const int m  = m0 + (ty << 2) + i;
            const int c0 = n0 + (tx << 2);
            float4 o = make_float4(acc[i][0] + bias[c0 + 0], acc[i][1] + bias[c0 + 1],
                                   acc[i][2] + bias[c0 + 2], acc[i][3] + bias[c0 + 3]);
            *(float4*)&C[(size_t)m * 256 + c0] = o;
        }
    }
}

extern "C" void kernel_launch(void* const* d_in, const int* in_sizes, int n_in,
                              void* d_out, int out_size, void* d_ws, size_t ws_size,
                              hipStream_t stream)
{
    const float* q  = (const float*)d_in[0];
    const float* k  = (const float*)d_in[1];
    const float* v  = (const float*)d_in[2];
    const float* Wi = (const float*)d_in[3];
    const float* bi = (const float*)d_in[4];
    const float* Wo = (const float*)d_in[5];
    const float* bo = (const float*)d_in[6];

    float* out      = (float*)d_out;
    float* attn_out = out;                 // [1024,4,256]
    float* cmask    = out + 1048576;       // [1024,1024]

    _Float16* Ppack    = (_Float16*)d_ws;
    float*    attn_pre = (float*)((char*)d_ws + 18874368);
    _Float16* pmask    = (_Float16*)((char*)d_ws + 23068672);
    _Float16* X16      = (_Float16*)((char*)d_ws + 90177536);
    _Float16* W16      = (_Float16*)((char*)d_ws + 96468992);

    cvt_kernel<<<1824, 256, 0, stream>>>(q, k, v, Wi, X16, W16);
    proj_kernel<<<dim3(18, 64), 256, 0, stream>>>(X16, W16, bi, Ppack);
    attn_kernel<<<2048, 512, 0, stream>>>(Ppack, attn_pre, pmask);
    tail_kernel<<<768, 256, 0, stream>>>(pmask, cmask, attn_pre, Wo, bo, attn_out);
}